// Round 8
// baseline (1823.680 us; speedup 1.0000x reference)
//
#include <hip/hip_runtime.h>
#include <stdint.h>

#define T_STEPS 200
#define OBSD    128
#define HID     128
#define LATD    32
#define BS_TOT  12800
#define KIN     160

#define OUT_ENT_OFF 81920000
#define OUT_LP_OFF  84480000

// lstm_main LDS layout (bytes)
#define H0_OFF  0          // 2 x 16384 : h tile [64][128] bf16, XOR-swizzled, dbuf
#define WMU_OFF 32768      // 8192      : W_mu bf16 [32][128], XOR-swizzled
#define E0_OFF  40960      // 2 x 4096  : eps bf16 A-fragment order, dbuf
#define LDS_SZ  49152

#define L2E  1.4426950408889634f
#define L2E2 2.8853900817779268f
#define LOG2PI 1.8378770664093453f

typedef short  bf16x8 __attribute__((ext_vector_type(8)));
typedef float  f32x4  __attribute__((ext_vector_type(4)));
typedef uint32_t u32;

// raw workgroup barrier: order LDS only, leave global loads/stores in flight
#define BAR() do {                                        \
    __builtin_amdgcn_sched_barrier(0);                    \
    asm volatile("s_waitcnt lgkmcnt(0)" ::: "memory");    \
    __builtin_amdgcn_s_barrier();                         \
    __builtin_amdgcn_sched_barrier(0);                    \
} while (0)

__device__ __forceinline__ uint16_t f2bf(float f) {
    u32 u = __builtin_bit_cast(u32, f);
    u32 r = (u + 0x7fffu + ((u >> 16) & 1u)) >> 16;
    return (uint16_t)r;
}
__device__ __forceinline__ float bf2f(u32 bits16) {
    u32 u = bits16 << 16;
    return __builtin_bit_cast(float, u);
}
__device__ __forceinline__ u32 pack2(float a, float b) {
    return (u32)f2bf(a) | ((u32)f2bf(b) << 16);
}
__device__ __forceinline__ u32 cvt_pk_bf16(float lo, float hi) {
    u32 r;
    asm("v_cvt_pk_bf16_f32 %0, %1, %2" : "=v"(r) : "v"(lo), "v"(hi));
    return r;
}
// x pre-scaled by L2E: sigmoid(x_true)
__device__ __forceinline__ float sig2(float x) {
    float e;
    asm("v_exp_f32 %0, -%1" : "=v"(e) : "v"(x));
    return __builtin_amdgcn_rcpf(1.f + e);
}
// x pre-scaled by 2*L2E: tanh(x_true)
__device__ __forceinline__ float tanh2(float x) {
    float e;
    asm("v_exp_f32 %0, %1" : "=v"(e) : "v"(x));
    return 1.f - 2.f * __builtin_amdgcn_rcpf(1.f + e);
}
// byte offset of h[row][col] in a [R][128] bf16 tile, XOR bank swizzle
__device__ __forceinline__ int hswz(int row, int col) {
    return ((row << 8) + (col << 1)) ^ ((row & 7) << 4);
}

// ---------------------------------------------------------------------------
// Kernel 1: xg = (x @ W_ihx^T + b_ih + b_hh + [t>0] zbias) * gate_scale, bf16,
// in the main kernel's fragment order. (unchanged, passing since round 5)
// ---------------------------------------------------------------------------
__global__ __launch_bounds__(512, 2) void xg_prep(
    const float* __restrict__ x,
    const float* __restrict__ W_ih,
    const float* __restrict__ b_ih,
    const float* __restrict__ b_hh,
    const float* __restrict__ b_mu,
    uint16_t* __restrict__ xg)
{
    const int blk = blockIdx.x;
    const int t   = blk >> 2, bq = blk & 3;
    const int tid = threadIdx.x;
    const int w = tid >> 6, l = tid & 63, lg = l >> 4, ln = l & 15;
    const int b0 = bq * 64;

    bf16x8 wb[4][4];
    float  bias[4];
    #pragma unroll
    for (int q = 0; q < 4; ++q) {
        const int col = q * 128 + w * 16 + ln;
        float zb = 0.f;
        #pragma unroll
        for (int j = 0; j < 32; ++j) zb += b_mu[j] * W_ih[col * KIN + 128 + j];
        bias[q] = b_ih[col] + b_hh[col] + (t > 0 ? zb : 0.f);
        #pragma unroll
        for (int ks = 0; ks < 4; ++ks) {
            bf16x8 v;
            #pragma unroll
            for (int e = 0; e < 8; ++e)
                v[e] = (short)f2bf(W_ih[col * KIN + ks * 32 + lg * 8 + e]);
            wb[ks][q] = v;
        }
    }

    f32x4 acc[4][4];
    const f32x4 vz = {0.f, 0.f, 0.f, 0.f};
    #pragma unroll
    for (int rt = 0; rt < 4; ++rt)
        #pragma unroll
        for (int q = 0; q < 4; ++q) acc[rt][q] = vz;

    #pragma unroll
    for (int ks = 0; ks < 4; ++ks) {
        bf16x8 a[4];
        #pragma unroll
        for (int rt = 0; rt < 4; ++rt) {
            const int brow = b0 + rt * 16 + ln;
            const float* src = x + ((size_t)brow * T_STEPS + t) * OBSD + ks * 32 + lg * 8;
            bf16x8 v;
            #pragma unroll
            for (int e = 0; e < 8; ++e) v[e] = (short)f2bf(src[e]);
            a[rt] = v;
        }
        #pragma unroll
        for (int rt = 0; rt < 4; ++rt)
            #pragma unroll
            for (int q = 0; q < 4; ++q)
                acc[rt][q] = __builtin_amdgcn_mfma_f32_16x16x32_bf16(
                    a[rt], wb[ks][q], acc[rt][q], 0, 0, 0);
    }

    const float gsc[4] = {L2E, L2E, L2E2, L2E};
    uint4* dst = (uint4*)xg + ((size_t)blk * 512 + tid) * 8;
    #pragma unroll
    for (int rt = 0; rt < 4; ++rt) {
        float v0[4], v1[4], v2[4], v3[4];
        #pragma unroll
        for (int e = 0; e < 4; ++e) {
            v0[e] = (acc[rt][0][e] + bias[0]) * gsc[0];
            v1[e] = (acc[rt][1][e] + bias[1]) * gsc[1];
            v2[e] = (acc[rt][2][e] + bias[2]) * gsc[2];
            v3[e] = (acc[rt][3][e] + bias[3]) * gsc[3];
        }
        uint4 o0, o1;
        o0.x = pack2(v0[0], v0[1]); o0.y = pack2(v0[2], v0[3]);
        o0.z = pack2(v1[0], v1[1]); o0.w = pack2(v1[2], v1[3]);
        o1.x = pack2(v2[0], v2[1]); o1.y = pack2(v2[2], v2[3]);
        o1.z = pack2(v3[0], v3[1]); o1.w = pack2(v3[2], v3[3]);
        dst[2 * rt]     = o0;
        dst[2 * rt + 1] = o1;
    }
}

// ---------------------------------------------------------------------------
// Kernel 2: entropies (const) + log_probs (eps-only) — fully parallel.
// ---------------------------------------------------------------------------
__global__ __launch_bounds__(256) void lp_ent(
    const float* __restrict__ eps,
    const float* __restrict__ cov,
    float* __restrict__ out)
{
    const int blk = blockIdx.x;
    const int rc = blk >> 2, tq = blk & 3;
    const int tid = threadIdx.x;
    const int c = tid & 3, rl = tid >> 2;
    const int row = rc * 64 + rl;

    float logdet = 0.f;
    for (int i = 0; i < LATD; ++i) logdet += logf(cov[i]);
    const float lconst = 32.f * LOG2PI + logdet;
    const float ec = 0.5f * 32.f * (1.f + LOG2PI) + 0.5f * logdet;

    const int t0 = tq * 50;
    for (int t = t0; t < t0 + 50; ++t) {
        const float* ep = eps + ((size_t)t * BS_TOT + row) * LATD + c * 8;
        const float4 a0 = *(const float4*)ep;
        const float4 a1 = *(const float4*)(ep + 4);
        float ps = a0.x*a0.x + a0.y*a0.y + a0.z*a0.z + a0.w*a0.w
                 + a1.x*a1.x + a1.y*a1.y + a1.z*a1.z + a1.w*a1.w;
        ps += __shfl_xor(ps, 1, 64);
        ps += __shfl_xor(ps, 2, 64);
        if (c == 0) {
            out[OUT_LP_OFF  + (size_t)row * 200 + t] = -0.5f * (ps + lconst);
            out[OUT_ENT_OFF + (size_t)row * 200 + t] = ec;
        }
    }
}

// ---------------------------------------------------------------------------
// Kernel 3: recurrence. 200 blocks x 512 threads (8 waves, 2/SIMD, 256-VGPR
// budget). Wr ENTIRELY in registers (no per-step weight LDS traffic).
// h + eps double-buffered in LDS -> ONE lgkm-only barrier per step.
// Wave w: cols q*128 + w*16 + ln (q=0..3), all 4 row-tiles; mean tile
// (rtm=w>>1, ctm=w&1) -> all 8 waves do one z tile.
// ---------------------------------------------------------------------------
__global__ __launch_bounds__(512, 2) void lstm_main(
    const float* __restrict__ eps,
    const float* __restrict__ W_ih,
    const float* __restrict__ W_hh,
    const float* __restrict__ W_mu,
    const float* __restrict__ b_mu,
    const float* __restrict__ cov,
    const uint16_t* __restrict__ xg,
    float* __restrict__ out)
{
    __shared__ __align__(16) char smem[LDS_SZ];

    const int tid = threadIdx.x;
    const int w = tid >> 6, l = tid & 63, lg = l >> 4, ln = l & 15;

    // XCD-aware bijective swizzle: same-bq blocks share an XCD pair
    const int xcd = blockIdx.x & 7;
    const int wk  = (xcd >> 1) + 4 * ((blockIdx.x >> 3) + 25 * (xcd & 1));
    const int bq  = wk & 3;
    const int bs0 = wk * 64;

    // stage W_mu f32 into H-buf0 region (16 KB) for the Wr build
    {
        float* ws = (float*)(smem + H0_OFF);
        for (int i = tid; i < 4096; i += 512) ws[i] = W_mu[i];
    }
    __syncthreads();
    const float* wmu_s = (const float*)(smem + H0_OFF);

    // W_mu bf16 region (swizzled), for the mean MFMA B-operand
    for (int i = tid; i < 2048; i += 512) {
        const int col = i >> 6, k2 = (i & 63) * 2;
        const u32 p = pack2(wmu_s[col * HID + k2], wmu_s[col * HID + k2 + 1]);
        *(u32*)(smem + WMU_OFF + (((col << 8) + (k2 << 1)) ^ ((col & 7) << 4))) = p;
    }

    // weg = std * W_ihz * gate_scale (B-frags, K=32), in regs
    bf16x8 weg[4];
    {
        float stds[8];
        #pragma unroll
        for (int e = 0; e < 8; ++e) stds[e] = sqrtf(cov[lg * 8 + e]);
        const float gsc[4] = {L2E, L2E, L2E2, L2E};
        #pragma unroll
        for (int q = 0; q < 4; ++q) {
            const int col = q * 128 + w * 16 + ln;
            bf16x8 v;
            #pragma unroll
            for (int e = 0; e < 8; ++e)
                v[e] = (short)f2bf(W_ih[col * KIN + 128 + lg * 8 + e] * stds[e] * gsc[q]);
            weg[q] = v;
        }
    }

    // Wr = (W_hh + W_ihz @ W_mu) * gate_scale -> REGISTERS (64 VGPR)
    bf16x8 wr[4][4];
    #pragma unroll
    for (int q = 0; q < 4; ++q) {
        const float gs = (q == 2) ? L2E2 : L2E;
        const int col = q * 128 + w * 16 + ln;
        float wzf[32];
        #pragma unroll
        for (int j4 = 0; j4 < 8; ++j4)
            *(float4*)&wzf[j4 * 4] = *(const float4*)&W_ih[col * KIN + 128 + j4 * 4];
        #pragma unroll
        for (int ks = 0; ks < 4; ++ks) {
            float base[8];
            *(float4*)&base[0] = *(const float4*)&W_hh[col * HID + ks * 32 + lg * 8];
            *(float4*)&base[4] = *(const float4*)&W_hh[col * HID + ks * 32 + lg * 8 + 4];
            bf16x8 v;
            #pragma unroll
            for (int e = 0; e < 8; ++e) {
                float s = base[e];
                #pragma unroll
                for (int j = 0; j < 32; ++j)
                    s += wzf[j] * wmu_s[j * HID + ks * 32 + lg * 8 + e];
                v[e] = (short)f2bf(s * gs);
            }
            wr[ks][q] = v;
        }
    }

    // mean-phase constants: wave w owns z tile (rtm, ctm)
    const int rtm = w >> 1, ctm = w & 1;
    const int zcol = ctm * 16 + ln;
    const float stdv = sqrtf(cov[zcol]);
    const float bmu  = b_mu[zcol];

    __syncthreads();   // WMU written; wmu_s reads done

    // zero h buf0 (overwrites wmu_s region) and E buf0
    for (int i = tid; i < 4096; i += 512) ((u32*)(smem + H0_OFF))[i] = 0;
    for (int i = tid; i < 1024; i += 512) ((u32*)(smem + E0_OFF))[i] = 0;

    const f32x4 vz4 = {0.f, 0.f, 0.f, 0.f};
    f32x4 cst[4] = {vz4, vz4, vz4, vz4};

    // eps loader map: thread -> (row erow, 4 latent dims ecol..ecol+3)
    const int erow = tid >> 3, ecol = (tid & 7) * 4;
    const int ert = erow >> 4;
    const int ewr = ((ert * 64 + (ecol >> 3) * 16 + (erow & 15)) << 4) + (ecol & 7) * 2;

    __syncthreads();   // zeros visible

    for (int t = 0; t < T_STEPS; ++t) {
        const int pb = t & 1;
        const char* Hp = smem + H0_OFF + pb * 16384;          // h_{t-1}
        char*       Hn = smem + H0_OFF + (pb ^ 1) * 16384;    // h_t
        const char* Ep = smem + E0_OFF + pb * 4096;           // eps_{t-1}
        char*       En = smem + E0_OFF + (pb ^ 1) * 4096;     // eps_t

        // ---- issue global loads (land under the MFMA phase) ----
        uint4 xv[8];
        const uint4* xp = (const uint4*)xg + ((size_t)(t * 4 + bq) * 512 + tid) * 8;
        #pragma unroll
        for (int i = 0; i < 8; ++i) xv[i] = xp[i];
        const float4 fe = *(const float4*)(eps + ((size_t)t * BS_TOT + bs0 + erow) * LATD + ecol);

        // ---- eg: eps_{t-1} @ weg^T (A-frags from Ep; zeros at t=0) ----
        f32x4 acc[4][4];
        #pragma unroll
        for (int rt = 0; rt < 4; ++rt) {
            const bf16x8 aE = *(const bf16x8*)(Ep + ((rt * 64 + l) << 4));
            #pragma unroll
            for (int q = 0; q < 4; ++q)
                acc[rt][q] = __builtin_amdgcn_mfma_f32_16x16x32_bf16(
                    aE, weg[q], vz4, 0, 0, 0);
        }
        // ---- gates: h_{t-1} @ Wr^T (B from registers!) ----
        #pragma unroll
        for (int ks = 0; ks < 4; ++ks) {
            bf16x8 a[4];
            #pragma unroll
            for (int rt = 0; rt < 4; ++rt)
                a[rt] = *(const bf16x8*)(Hp + hswz(rt * 16 + ln, ks * 32 + lg * 8));
            #pragma unroll
            for (int rt = 0; rt < 4; ++rt)
                #pragma unroll
                for (int q = 0; q < 4; ++q)
                    acc[rt][q] = __builtin_amdgcn_mfma_f32_16x16x32_bf16(
                        a[rt], wr[ks][q], acc[rt][q], 0, 0, 0);
        }
        // ---- mean/z for t-1 (reads Hp/Ep, off critical path) ----
        if (t > 0) {
            f32x4 macc = vz4;
            #pragma unroll
            for (int ks = 0; ks < 4; ++ks) {
                const bf16x8 am = *(const bf16x8*)(Hp + hswz(rtm * 16 + ln, ks * 32 + lg * 8));
                const bf16x8 bm = *(const bf16x8*)(smem + WMU_OFF + hswz(zcol, ks * 32 + lg * 8));
                macc = __builtin_amdgcn_mfma_f32_16x16x32_bf16(am, bm, macc, 0, 0, 0);
            }
            #pragma unroll
            for (int e = 0; e < 4; ++e) {
                const int row = rtm * 16 + lg * 4 + e;
                const float evv = bf2f(*(const uint16_t*)(
                    Ep + ((rtm * 64 + (zcol >> 3) * 16 + (lg * 4 + e)) << 4) + (zcol & 7) * 2));
                out[(size_t)(bs0 + row) * 6400 + (t - 1) * 32 + zcol] =
                    macc[e] + bmu + evv * stdv;
            }
        }

        // ---- LSTM elementwise (writes h_t into Hn: other buffer, no race) --
        #pragma unroll
        for (int rt = 0; rt < 4; ++rt) {
            const uint4 u01 = xv[2 * rt], u23 = xv[2 * rt + 1];
            const float xi[4] = { bf2f(u01.x & 0xffff), bf2f(u01.x >> 16),
                                  bf2f(u01.y & 0xffff), bf2f(u01.y >> 16) };
            const float xf[4] = { bf2f(u01.z & 0xffff), bf2f(u01.z >> 16),
                                  bf2f(u01.w & 0xffff), bf2f(u01.w >> 16) };
            const float xgv[4] = { bf2f(u23.x & 0xffff), bf2f(u23.x >> 16),
                                   bf2f(u23.y & 0xffff), bf2f(u23.y >> 16) };
            const float xo[4] = { bf2f(u23.z & 0xffff), bf2f(u23.z >> 16),
                                  bf2f(u23.w & 0xffff), bf2f(u23.w >> 16) };
            #pragma unroll
            for (int e = 0; e < 4; ++e) {
                const float iv = acc[rt][0][e] + xi[e];
                const float fv = acc[rt][1][e] + xf[e];
                const float gv = acc[rt][2][e] + xgv[e];
                const float ov = acc[rt][3][e] + xo[e];
                const float c  = sig2(fv) * cst[rt][e] + sig2(iv) * tanh2(gv);
                cst[rt][e] = c;
                const float h = sig2(ov) * tanh2(c * L2E2);
                const int row = rt * 16 + lg * 4 + e;
                *(uint16_t*)(Hn + hswz(row, w * 16 + ln)) = f2bf(h);
            }
        }

        // ---- store eps_t (bf16 A-frag order) into En ----
        {
            uint2 p;
            p.x = cvt_pk_bf16(fe.x, fe.y);
            p.y = cvt_pk_bf16(fe.z, fe.w);
            *(uint2*)(En + ewr) = p;
        }

        BAR();   // ONE barrier per step: Hn/En visible; globals stay in flight
    }

    // epilogue: z for t = 199 (h_199 / eps_199 live in buf[T_STEPS & 1])
    {
        const char* Hp = smem + H0_OFF + (T_STEPS & 1) * 16384;
        const char* Ep = smem + E0_OFF + (T_STEPS & 1) * 4096;
        f32x4 macc = vz4;
        #pragma unroll
        for (int ks = 0; ks < 4; ++ks) {
            const bf16x8 am = *(const bf16x8*)(Hp + hswz(rtm * 16 + ln, ks * 32 + lg * 8));
            const bf16x8 bm = *(const bf16x8*)(smem + WMU_OFF + hswz(zcol, ks * 32 + lg * 8));
            macc = __builtin_amdgcn_mfma_f32_16x16x32_bf16(am, bm, macc, 0, 0, 0);
        }
        #pragma unroll
        for (int e = 0; e < 4; ++e) {
            const int row = rtm * 16 + lg * 4 + e;
            const float evv = bf2f(*(const uint16_t*)(
                Ep + ((rtm * 64 + (zcol >> 3) * 16 + (lg * 4 + e)) << 4) + (zcol & 7) * 2));
            out[(size_t)(bs0 + row) * 6400 + 199 * 32 + zcol] =
                macc[e] + bmu + evv * stdv;
        }
    }
}

extern "C" void kernel_launch(void* const* d_in, const int* in_sizes, int n_in,
                              void* d_out, int out_size, void* d_ws, size_t ws_size,
                              hipStream_t stream) {
    const float* x    = (const float*)d_in[0];
    const float* eps  = (const float*)d_in[1];
    const float* W_ih = (const float*)d_in[2];
    const float* W_hh = (const float*)d_in[3];
    const float* b_ih = (const float*)d_in[4];
    const float* b_hh = (const float*)d_in[5];
    const float* W_mu = (const float*)d_in[6];
    const float* b_mu = (const float*)d_in[7];
    const float* cov  = (const float*)d_in[8];
    float* out = (float*)d_out;
    uint16_t* xg = (uint16_t*)d_ws;   // 52,428,800 bytes

    hipLaunchKernelGGL(xg_prep, dim3(800), dim3(512), 0, stream, x, W_ih, b_ih, b_hh, b_mu, xg);
    hipLaunchKernelGGL(lp_ent, dim3(800), dim3(256), 0, stream, eps, cov, out);
    hipLaunchKernelGGL(lstm_main, dim3(200), dim3(512), 0, stream,
                       eps, W_ih, W_hh, W_mu, b_mu, cov, xg, out);
}